// Round 1
// baseline (5440.665 us; speedup 1.0000x reference)
//
#include <hip/hip_runtime.h>

// Problem constants
constexpr int CIN   = 256;   // feature channels
constexpr int KD    = 32;    // key dim
constexpr int VD    = 128;   // value dim
constexpr int NCLS  = 10;
constexpr int BS    = 4;
constexpr int HW    = 256;   // 16*16
constexpr float BNC = 0.9999950000374997f; // 1/sqrt(1+1e-5)

static __device__ __forceinline__ int imin(int a, int b) { return a < b ? a : b; }

// ---------------------------------------------------------------------------
// conv3x3, pad=1, on 16x16 images, Cin=256. grid.x = B * (OC/8), block=256.
// out[(b*outC + oc)*256 + pix] = (conv + bias[oc]) * scale
__global__ __launch_bounds__(256) void k_conv3x3(
    const float* __restrict__ in, const float* __restrict__ w,
    const float* __restrict__ bias, float* __restrict__ out,
    int OC, int outC, float scale) {
  int nt  = OC >> 3;
  int b   = blockIdx.x / nt;
  int ocg = blockIdx.x % nt;
  int tid = threadIdx.x;
  int y = tid >> 4, x = tid & 15;

  __shared__ float sm[8][18][18];
  for (int i = tid; i < 8 * 18 * 18; i += 256) ((float*)sm)[i] = 0.f;

  float acc[8] = {0.f, 0.f, 0.f, 0.f, 0.f, 0.f, 0.f, 0.f};
  const float* inb = in + (size_t)b * CIN * HW;

  for (int cg = 0; cg < 32; ++cg) {
    __syncthreads();   // covers zero-fill on first iter, compute on later iters
#pragma unroll
    for (int pch = 0; pch < 8; ++pch)
      sm[pch][y + 1][x + 1] = inb[(cg * 8 + pch) * HW + tid];
    __syncthreads();
#pragma unroll
    for (int pch = 0; pch < 8; ++pch) {
      float r0 = sm[pch][y][x],     r1 = sm[pch][y][x + 1],     r2 = sm[pch][y][x + 2];
      float r3 = sm[pch][y + 1][x], r4 = sm[pch][y + 1][x + 1], r5 = sm[pch][y + 1][x + 2];
      float r6 = sm[pch][y + 2][x], r7 = sm[pch][y + 2][x + 1], r8 = sm[pch][y + 2][x + 2];
      int c = cg * 8 + pch;
#pragma unroll
      for (int o = 0; o < 8; ++o) {
        const float* wp = w + ((size_t)(ocg * 8 + o) * CIN + c) * 9;
        acc[o] += wp[0] * r0 + wp[1] * r1 + wp[2] * r2
                + wp[3] * r3 + wp[4] * r4 + wp[5] * r5
                + wp[6] * r6 + wp[7] * r7 + wp[8] * r8;
      }
    }
  }
  for (int o = 0; o < 8; ++o) {
    int oc = ocg * 8 + o;
    out[((size_t)b * outC + oc) * HW + tid] = (acc[o] + bias[oc]) * scale;
  }
}

// ---------------------------------------------------------------------------
// bilinear align_corners resize of planes to 16x16. total = planes*256.
__global__ __launch_bounds__(256) void k_resize16(
    const float* __restrict__ in, float* __restrict__ out, int total, int Hin, int Win) {
  int idx = blockIdx.x * 256 + threadIdx.x;
  if (idx >= total) return;
  int pos = idx & 255, pl = idx >> 8;
  int Y = pos >> 4, X = pos & 15;
  float cyf = (float)(Y * (Hin - 1)) / 15.0f;
  int ylo = imin((int)cyf, Hin - 2); float fy = cyf - (float)ylo;
  float cxf = (float)(X * (Win - 1)) / 15.0f;
  int xlo = imin((int)cxf, Win - 2); float fx = cxf - (float)xlo;
  const float* pb = in + (size_t)pl * Hin * Win;
  float v0 = pb[ylo * Win + xlo],       v1 = pb[ylo * Win + xlo + 1];
  float v2 = pb[(ylo + 1) * Win + xlo], v3 = pb[(ylo + 1) * Win + xlo + 1];
  out[idx] = (1.f - fy) * ((1.f - fx) * v0 + fx * v1)
           + fy * ((1.f - fx) * v2 + fx * v3);
}

// ---------------------------------------------------------------------------
// p[b,n,i,j] = sum_k kq[b,k,i]*kt[n,k,j]; also online max m[bn,j], sum s[bn,j]
// grid = BS*NCLS, block = 256 (thread = j)
__global__ __launch_bounds__(256) void k_pms(
    const float* __restrict__ kq, const float* __restrict__ kt,
    float* __restrict__ p, float* __restrict__ mo, float* __restrict__ so) {
  int bn = blockIdx.x;
  int b = bn / NCLS, n = bn % NCLS;
  int j = threadIdx.x;
  __shared__ float kqs[KD][HW];
  float ktr[KD];
#pragma unroll
  for (int k = 0; k < KD; ++k) ktr[k] = kt[((size_t)n * KD + k) * HW + j];
#pragma unroll
  for (int k = 0; k < KD; ++k) kqs[k][j] = kq[((size_t)b * KD + k) * HW + j];
  __syncthreads();
  float m = -1e30f, s = 0.f;
  float* prow = p + (size_t)bn * HW * HW + j;
  for (int i = 0; i < HW; ++i) {
    float v = 0.f;
#pragma unroll
    for (int k = 0; k < KD; ++k) v += kqs[k][i] * ktr[k];
    prow[i * HW] = v;
    float mn = fmaxf(m, v);
    s = s * __expf(m - mn) + __expf(v - mn);
    m = mn;
  }
  mo[bn * HW + j] = m;
  so[bn * HW + j] = s;
}

// p normalize in place: p = exp(p - m[bn,j]) / s[bn,j]
__global__ __launch_bounds__(256) void k_pnorm(
    float* __restrict__ p, const float* __restrict__ mo, const float* __restrict__ so) {
  int idx = blockIdx.x * 256 + threadIdx.x;
  int j = idx & 255;
  int bn = idx >> 16;
  int msi = bn * HW + j;
  p[idx] = __expf(p[idx] - mo[msi]) / so[msi];
}

// ---------------------------------------------------------------------------
// fa[b,n,j,Y,X] = bilinear_{YX <- 16x16 over i}( p[b,n,i,j] )
__global__ __launch_bounds__(256) void k_fa(
    const float* __restrict__ p, float* __restrict__ out, int S, int shift) {
  int idx = blockIdx.x * 256 + threadIdx.x;
  int X = idx & (S - 1);
  int Y = (idx >> shift) & (S - 1);
  int j = (idx >> (2 * shift)) & 255;
  int bn = idx >> (2 * shift + 8);
  float cyf = (float)(Y * 15) / (float)(S - 1);
  int ylo = imin((int)cyf, 14); float fy = cyf - (float)ylo;
  float cxf = (float)(X * 15) / (float)(S - 1);
  int xlo = imin((int)cxf, 14); float fx = cxf - (float)xlo;
  const float* base = p + (size_t)bn * HW * HW + j;
  int o00 = (ylo * 16 + xlo) * HW;
  float v0 = base[o00],            v1 = base[o00 + HW];
  float v2 = base[o00 + 16 * HW],  v3 = base[o00 + 17 * HW];
  out[idx] = (1.f - fy) * ((1.f - fx) * v0 + fx * v1)
           + fy * ((1.f - fx) * v2 + fx * v3);
}

// ---------------------------------------------------------------------------
// aggn[b,n,c,j] = sum_i vt[n,c,i] * p[b,n,i,j]. grid = BS*NCLS*8 (ctile 16)
__global__ __launch_bounds__(256) void k_aggn(
    const float* __restrict__ vt, const float* __restrict__ p, float* __restrict__ aggn) {
  int blk = blockIdx.x;
  int ct = blk & 7, bn = blk >> 3;
  int n = bn % NCLS;
  int j = threadIdx.x;
  __shared__ float vts[16][HW];
  for (int c = 0; c < 16; ++c) vts[c][j] = vt[((size_t)n * VD + ct * 16 + c) * HW + j];
  __syncthreads();
  float acc[16] = {};
  const float* pp = p + (size_t)bn * HW * HW + j;
  for (int i = 0; i < HW; ++i) {
    float pv = pp[i * HW];
#pragma unroll
    for (int c = 0; c < 16; ++c) acc[c] += vts[c][i] * pv;
  }
  for (int c = 0; c < 16; ++c)
    aggn[((size_t)bn * VD + ct * 16 + c) * HW + j] = acc[c];
}

// final16[b, 128+c, j] = sum_n aggn[b,n,c,j].  total = BS*VD*HW = 131072
__global__ __launch_bounds__(256) void k_aggred(
    const float* __restrict__ aggn, float* __restrict__ f16) {
  int idx = blockIdx.x * 256 + threadIdx.x;
  int j = idx & 255;
  int c = (idx >> 8) & 127;
  int b = idx >> 15;
  float s = 0.f;
  for (int n = 0; n < NCLS; ++n)
    s += aggn[(((size_t)b * NCLS + n) * VD + c) * HW + j];
  f16[((size_t)b * CIN + VD + c) * HW + j] = s;
}

// ---------------------------------------------------------------------------
// g16[b,oc,j] = sum_c cw[oc,256+c] * (gamma[c]*BNC) * f16[b,c,j]
// grid = BS*16, block = 256 (thread = j)
__global__ __launch_bounds__(256) void k_g16(
    const float* __restrict__ f16, const float* __restrict__ cw,
    const float* __restrict__ gamma, float* __restrict__ g16) {
  int b = blockIdx.x >> 4, ocg = blockIdx.x & 15;
  int j = threadIdx.x;
  float acc[16] = {};
  for (int c = 0; c < CIN; ++c) {
    float fv = f16[((size_t)b * CIN + c) * HW + j] * (gamma[c] * BNC);
#pragma unroll
    for (int o = 0; o < 16; ++o)
      acc[o] += cw[(size_t)(ocg * 16 + o) * 512 + 256 + c] * fv;
  }
  for (int o = 0; o < 16; ++o)
    g16[((size_t)b * CIN + ocg * 16 + o) * HW + j] = acc[o];
}

// cb[l,oc] = combine_b[oc] + sum_c cw[oc,256+c]*beta[l,c].  grid=5, block=256
__global__ __launch_bounds__(256) void k_cb(
    const float* __restrict__ cw, const float* __restrict__ cbias,
    const float* __restrict__ beta, float* __restrict__ cb) {
  int l = blockIdx.x, oc = threadIdx.x;
  float s = cbias[oc];
  for (int c = 0; c < CIN; ++c)
    s += cw[(size_t)oc * 512 + 256 + c] * beta[l * CIN + c];
  cb[l * CIN + oc] = s;
}

// ---------------------------------------------------------------------------
// out[b,oc,Y,X] = sum_c cw[oc,c]*f[b,c,Y,X] + bilinear(g16[b,oc])(Y,X) + cb[oc]
// grid = BS*16*chunks
__global__ __launch_bounds__(256) void k_out(
    const float* __restrict__ f, const float* __restrict__ cw,
    const float* __restrict__ g16, const float* __restrict__ cb,
    float* __restrict__ out, int S, int shift, int chunks) {
  int blk = blockIdx.x;
  int ch = blk % chunks;
  int t = blk / chunks;
  int ocg = t & 15, b = t >> 4;
  int pix = ch * 256 + threadIdx.x;
  int SS = S * S;
  if (pix >= SS) return;
  int X = pix & (S - 1), Y = pix >> shift;
  float acc[16] = {};
  const float* fb = f + (size_t)b * CIN * SS + pix;
  for (int c = 0; c < CIN; ++c) {
    float fv = fb[(size_t)c * SS];
#pragma unroll
    for (int o = 0; o < 16; ++o)
      acc[o] += cw[(size_t)(ocg * 16 + o) * 512 + c] * fv;
  }
  float cyf = (float)(Y * 15) / (float)(S - 1);
  int ylo = imin((int)cyf, 14); float fy = cyf - (float)ylo;
  float cxf = (float)(X * 15) / (float)(S - 1);
  int xlo = imin((int)cxf, 14); float fx = cxf - (float)xlo;
  const float* gb = g16 + ((size_t)b * CIN + ocg * 16) * HW + ylo * 16 + xlo;
  for (int o = 0; o < 16; ++o) {
    const float* g = gb + (size_t)o * HW;
    float v0 = g[0], v1 = g[1], v2 = g[16], v3 = g[17];
    float bil = (1.f - fy) * ((1.f - fx) * v0 + fx * v1)
              + fy * ((1.f - fx) * v2 + fx * v3);
    out[((size_t)b * CIN + ocg * 16 + o) * SS + pix] = acc[o] + bil + cb[ocg * 16 + o];
  }
}

// ===========================================================================
extern "C" void kernel_launch(void* const* d_in, const int* in_sizes, int n_in,
                              void* d_out, int out_size, void* d_ws, size_t ws_size,
                              hipStream_t stream) {
  const float* feat[5];
  for (int l = 0; l < 5; ++l) feat[l] = (const float*)d_in[l];
  const float* att   = (const float*)d_in[5];
  const float* ktw   = (const float*)d_in[6];
  const float* ktb   = (const float*)d_in[7];
  const float* vtw   = (const float*)d_in[8];
  const float* vtb   = (const float*)d_in[9];
  const float* kqw   = (const float*)d_in[10];
  const float* kqb   = (const float*)d_in[11];
  const float* vqw   = (const float*)d_in[12];
  const float* vqb   = (const float*)d_in[13];
  const float* gamma = (const float*)d_in[14];
  const float* beta  = (const float*)d_in[15];
  const float* cw    = (const float*)d_in[16];
  const float* cbias = (const float*)d_in[17];
  float* out = (float*)d_out;

  // workspace layout (floats)
  float* ws   = (float*)d_ws;
  float* kt   = ws;                 // 10*32*256      = 81920
  float* vt   = kt  + 81920;        // 10*128*256     = 327680
  float* fr   = vt  + 327680;       // 4*256*256      = 262144
  float* kq   = fr  + 262144;       // 4*32*256       = 32768
  float* f16  = kq  + 32768;        // 4*256*256      = 262144
  float* p    = f16 + 262144;       // 4*10*256*256   = 2621440
  float* mo   = p   + 2621440;      // 10240
  float* so   = mo  + 10240;        // 10240
  float* aggn = so  + 10240;        // 4*10*128*256   = 1310720
  float* g16  = aggn + 1310720;     // 262144
  float* cb   = g16 + 262144;       // 1280

  static const int sizes[5]  = {64, 32, 16, 8, 4};
  static const int shifts[5] = {6, 5, 4, 3, 2};
  size_t out_off[5], fa_off[5];
  {
    size_t off = 0;
    for (int l = 0; l < 5; ++l) { out_off[l] = off; off += (size_t)BS * CIN * sizes[l] * sizes[l]; }
    for (int l = 0; l < 5; ++l) { fa_off[l] = off; off += (size_t)BS * NCLS * HW * sizes[l] * sizes[l]; }
  }

  // templates (shared across levels)
  k_conv3x3<<<NCLS * (KD / 8), 256, 0, stream>>>(att, ktw, ktb, kt, KD, KD, 1.f);
  k_conv3x3<<<NCLS * (VD / 8), 256, 0, stream>>>(att, vtw, vtb, vt, VD, VD, 1.f);
  k_cb<<<5, 256, 0, stream>>>(cw, cbias, beta, cb);

  for (int l = 0; l < 5; ++l) {
    int S = sizes[l], sh = shifts[l], SS = S * S;
    k_resize16<<<(BS * CIN * HW) / 256, 256, 0, stream>>>(feat[l], fr, BS * CIN * HW, S, S);
    k_conv3x3<<<BS * (KD / 8), 256, 0, stream>>>(
        fr, kqw + (size_t)l * KD * CIN * 9, kqb + l * KD, kq, KD, KD, 1.f);
    k_conv3x3<<<BS * (VD / 8), 256, 0, stream>>>(
        fr, vqw + (size_t)l * VD * CIN * 9, vqb + l * VD, f16, VD, CIN, (float)NCLS);
    k_pms<<<BS * NCLS, 256, 0, stream>>>(kq, kt, p, mo, so);
    k_pnorm<<<(BS * NCLS * HW * HW) / 256, 256, 0, stream>>>(p, mo, so);
    int fatot = BS * NCLS * HW * SS;
    k_fa<<<fatot / 256, 256, 0, stream>>>(p, out + fa_off[l], S, sh);
    k_aggn<<<BS * NCLS * 8, 256, 0, stream>>>(vt, p, aggn);
    k_aggred<<<(BS * VD * HW) / 256, 256, 0, stream>>>(aggn, f16);
    k_g16<<<BS * 16, 256, 0, stream>>>(f16, cw, gamma + l * CIN, g16);
    int chunks = (SS + 255) / 256;
    k_out<<<BS * 16 * chunks, 256, 0, stream>>>(
        feat[l], cw, g16, cb + l * CIN, out + out_off[l], S, sh, chunks);
  }
}

// Round 2
// 2188.890 us; speedup vs baseline: 2.4856x; 2.4856x over previous
//
#include <hip/hip_runtime.h>

// Problem constants
constexpr int CIN   = 256;   // feature channels
constexpr int KD    = 32;    // key dim
constexpr int VD    = 128;   // value dim
constexpr int NCLS  = 10;
constexpr int BS    = 4;
constexpr int HW    = 256;   // 16*16
constexpr int KS    = 8;     // conv input-channel splits
constexpr int CPB   = 32;    // conv channels per block
constexpr float BNC = 0.9999950000374997f; // 1/sqrt(1+1e-5)

static __device__ __forceinline__ int imin(int a, int b) { return a < b ? a : b; }

// ---------------------------------------------------------------------------
// conv3x3 partial: pad=1, 16x16 images, CPB input channels per block.
// grid.x = nImg * (OC/8) * KS, block = 256.
// part[((ks*nImg + b)*OC + oc)*256 + pix] = partial conv over channels [ks*CPB, +CPB)
__global__ __launch_bounds__(256) void k_conv_part(
    const float* __restrict__ in, const float* __restrict__ w,
    float* __restrict__ part, int OC, int nImg) {
  int nt  = OC >> 3;
  int b   = blockIdx.x / (nt * KS);
  int rem = blockIdx.x % (nt * KS);
  int ks  = rem / nt, ocg = rem % nt;
  int tid = threadIdx.x;
  int y = tid >> 4, x = tid & 15;

  __shared__ float sm[8][18][18];
  for (int i = tid; i < 8 * 18 * 18; i += 256) ((float*)sm)[i] = 0.f;

  float acc[8] = {};
  const float* inb = in + ((size_t)b * CIN + ks * CPB) * HW;
  const float* wb  = w + ((size_t)(ocg * 8) * CIN + ks * CPB) * 9;

  for (int cg = 0; cg < CPB / 8; ++cg) {
    __syncthreads();
#pragma unroll
    for (int pch = 0; pch < 8; ++pch)
      sm[pch][y + 1][x + 1] = inb[(cg * 8 + pch) * HW + tid];
    __syncthreads();
#pragma unroll
    for (int pch = 0; pch < 8; ++pch) {
      float r0 = sm[pch][y][x],     r1 = sm[pch][y][x + 1],     r2 = sm[pch][y][x + 2];
      float r3 = sm[pch][y + 1][x], r4 = sm[pch][y + 1][x + 1], r5 = sm[pch][y + 1][x + 2];
      float r6 = sm[pch][y + 2][x], r7 = sm[pch][y + 2][x + 1], r8 = sm[pch][y + 2][x + 2];
      int c = cg * 8 + pch;
#pragma unroll
      for (int o = 0; o < 8; ++o) {
        const float* wp = wb + ((size_t)o * CIN + c) * 9;   // wave-uniform -> s_load
        acc[o] += wp[0] * r0 + wp[1] * r1 + wp[2] * r2
                + wp[3] * r3 + wp[4] * r4 + wp[5] * r5
                + wp[6] * r6 + wp[7] * r7 + wp[8] * r8;
      }
    }
  }
  for (int o = 0; o < 8; ++o)
    part[(((size_t)ks * nImg + b) * OC + ocg * 8 + o) * HW + tid] = acc[o];
}

// reduce over KS partials, add bias, scale. total = nImg*OC*HW
__global__ __launch_bounds__(256) void k_conv_red(
    const float* __restrict__ part, const float* __restrict__ bias,
    float* __restrict__ out, int OC, int nImg, int outC, float scale) {
  int idx = blockIdx.x * 256 + threadIdx.x;
  int pix = idx & 255;
  int oc  = (idx >> 8) % OC;
  int b   = idx / (OC * HW);
  size_t stride = (size_t)nImg * OC * HW;
  const float* pp = part + idx;
  float s = 0.f;
#pragma unroll
  for (int k = 0; k < KS; ++k) s += pp[k * stride];
  out[((size_t)b * outC + oc) * HW + pix] = (s + bias[oc]) * scale;
}

// ---------------------------------------------------------------------------
// bilinear align_corners resize of planes to 16x16. total = planes*256.
__global__ __launch_bounds__(256) void k_resize16(
    const float* __restrict__ in, float* __restrict__ out, int total, int Hin, int Win) {
  int idx = blockIdx.x * 256 + threadIdx.x;
  if (idx >= total) return;
  int pos = idx & 255, pl = idx >> 8;
  int Y = pos >> 4, X = pos & 15;
  float cyf = (float)(Y * (Hin - 1)) / 15.0f;
  int ylo = imin((int)cyf, Hin - 2); float fy = cyf - (float)ylo;
  float cxf = (float)(X * (Win - 1)) / 15.0f;
  int xlo = imin((int)cxf, Win - 2); float fx = cxf - (float)xlo;
  const float* pb = in + (size_t)pl * Hin * Win;
  float v0 = pb[ylo * Win + xlo],       v1 = pb[ylo * Win + xlo + 1];
  float v2 = pb[(ylo + 1) * Win + xlo], v3 = pb[(ylo + 1) * Win + xlo + 1];
  out[idx] = (1.f - fy) * ((1.f - fx) * v0 + fx * v1)
           + fy * ((1.f - fx) * v2 + fx * v3);
}

// ---------------------------------------------------------------------------
// p partial + online softmax stats, i-split by 4.
// grid = BS*NCLS*4, block = 256 (thread = j)
__global__ __launch_bounds__(256) void k_pms_part(
    const float* __restrict__ kq, const float* __restrict__ kt,
    float* __restrict__ p, float* __restrict__ mp, float* __restrict__ sp) {
  int blk = blockIdx.x;
  int it = blk & 3, bn = blk >> 2;
  int b = bn / NCLS, n = bn % NCLS;
  int j = threadIdx.x;
  __shared__ float kqs[KD][64];
  float ktr[KD];
#pragma unroll
  for (int k = 0; k < KD; ++k) ktr[k] = kt[((size_t)n * KD + k) * HW + j];
  for (int t = j; t < KD * 64; t += 256) {
    int k = t >> 6, ii = t & 63;
    kqs[k][ii] = kq[((size_t)b * KD + k) * HW + it * 64 + ii];
  }
  __syncthreads();
  float m = -1e30f, s = 0.f;
  float* prow = p + (size_t)bn * HW * HW + (size_t)it * 64 * HW + j;
  for (int i = 0; i < 64; ++i) {
    float v = 0.f;
#pragma unroll
    for (int k = 0; k < KD; ++k) v += kqs[k][i] * ktr[k];
    prow[i * HW] = v;
    float mn = fmaxf(m, v);
    s = s * __expf(m - mn) + __expf(v - mn);
    m = mn;
  }
  mp[blk * HW + j] = m;
  sp[blk * HW + j] = s;
}

// merge 4 partial (m,s) pairs. total = BS*NCLS*HW
__global__ __launch_bounds__(256) void k_msmerge(
    const float* __restrict__ mp, const float* __restrict__ sp,
    float* __restrict__ mo, float* __restrict__ so) {
  int idx = blockIdx.x * 256 + threadIdx.x;
  int bn = idx >> 8, j = idx & 255;
  float m = -1e30f, s = 0.f;
#pragma unroll
  for (int t = 0; t < 4; ++t) {
    float mt = mp[(bn * 4 + t) * HW + j], st = sp[(bn * 4 + t) * HW + j];
    float mn = fmaxf(m, mt);
    s = s * __expf(m - mn) + st * __expf(mt - mn);
    m = mn;
  }
  mo[idx] = m; so[idx] = s;
}

// p normalize in place: p = exp(p - m[bn,j]) / s[bn,j]
__global__ __launch_bounds__(256) void k_pnorm(
    float* __restrict__ p, const float* __restrict__ mo, const float* __restrict__ so) {
  int idx = blockIdx.x * 256 + threadIdx.x;
  int j = idx & 255;
  int bn = idx >> 16;
  int msi = bn * HW + j;
  p[idx] = __expf(p[idx] - mo[msi]) / so[msi];
}

// ---------------------------------------------------------------------------
// fa[b,n,j,Y,X] = bilinear(p[b,n,:,j]) ; 4 outputs per thread, float4 store
__global__ __launch_bounds__(256) void k_fa4(
    const float* __restrict__ p, float* __restrict__ out, int S, int shift) {
  int e = (blockIdx.x * 256 + threadIdx.x) * 4;
  int X0 = e & (S - 1);
  int Y = (e >> shift) & (S - 1);
  int j = (e >> (2 * shift)) & 255;
  int bn = e >> (2 * shift + 8);
  float cyf = (float)(Y * 15) / (float)(S - 1);
  int ylo = imin((int)cyf, 14); float fy = cyf - (float)ylo;
  const float* base = p + (size_t)bn * HW * HW + j + (size_t)(ylo * 16) * HW;
  float4 r;
  float* rr = (float*)&r;
#pragma unroll
  for (int t = 0; t < 4; ++t) {
    int X = X0 + t;
    float cxf = (float)(X * 15) / (float)(S - 1);
    int xlo = imin((int)cxf, 14); float fx = cxf - (float)xlo;
    const float* g = base + (size_t)xlo * HW;
    float v0 = g[0],           v1 = g[HW];
    float v2 = g[16 * HW],     v3 = g[17 * HW];
    rr[t] = (1.f - fy) * ((1.f - fx) * v0 + fx * v1)
          + fy * ((1.f - fx) * v2 + fx * v3);
  }
  *(float4*)(out + e) = r;
}

// ---------------------------------------------------------------------------
// aggn[b,n,c,j] = sum_i vt[n,c,i] * p[b,n,i,j]. grid = BS*NCLS*8 (ctile 16)
__global__ __launch_bounds__(256) void k_aggn(
    const float* __restrict__ vt, const float* __restrict__ p, float* __restrict__ aggn) {
  int blk = blockIdx.x;
  int ct = blk & 7, bn = blk >> 3;
  int n = bn % NCLS;
  int j = threadIdx.x;
  __shared__ float vts[16][HW];
  for (int c = 0; c < 16; ++c) vts[c][j] = vt[((size_t)n * VD + ct * 16 + c) * HW + j];
  __syncthreads();
  float acc[16] = {};
  const float* pp = p + (size_t)bn * HW * HW + j;
  for (int i = 0; i < HW; ++i) {
    float pv = pp[i * HW];
#pragma unroll
    for (int c = 0; c < 16; ++c) acc[c] += vts[c][i] * pv;
  }
  for (int c = 0; c < 16; ++c)
    aggn[((size_t)bn * VD + ct * 16 + c) * HW + j] = acc[c];
}

// final16[b, 128+c, j] = sum_n aggn[b,n,c,j].  total = BS*VD*HW = 131072
__global__ __launch_bounds__(256) void k_aggred(
    const float* __restrict__ aggn, float* __restrict__ f16) {
  int idx = blockIdx.x * 256 + threadIdx.x;
  int j = idx & 255;
  int c = (idx >> 8) & 127;
  int b = idx >> 15;
  float s = 0.f;
#pragma unroll
  for (int n = 0; n < NCLS; ++n)
    s += aggn[(((size_t)b * NCLS + n) * VD + c) * HW + j];
  f16[((size_t)b * CIN + VD + c) * HW + j] = s;
}

// ---------------------------------------------------------------------------
// g16[b,oc,j] = sum_c cw[oc,256+c] * (gamma[c]*BNC) * f16[b,c,j]
// grid = BS*32, block = 256 (thread = j), 8 oc per block
__global__ __launch_bounds__(256) void k_g16(
    const float* __restrict__ f16, const float* __restrict__ cw,
    const float* __restrict__ gamma, float* __restrict__ g16) {
  int b = blockIdx.x >> 5, ocg = blockIdx.x & 31;
  int j = threadIdx.x;
  float acc[8] = {};
  for (int c = 0; c < CIN; ++c) {
    float fv = f16[((size_t)b * CIN + c) * HW + j] * (gamma[c] * BNC);
#pragma unroll
    for (int o = 0; o < 8; ++o)
      acc[o] += cw[(size_t)(ocg * 8 + o) * 512 + 256 + c] * fv;
  }
  for (int o = 0; o < 8; ++o)
    g16[((size_t)b * CIN + ocg * 8 + o) * HW + j] = acc[o];
}

// cb[l,oc] = combine_b[oc] + sum_c cw[oc,256+c]*beta[l,c].  grid=5, block=256
__global__ __launch_bounds__(256) void k_cb(
    const float* __restrict__ cw, const float* __restrict__ cbias,
    const float* __restrict__ beta, float* __restrict__ cb) {
  int l = blockIdx.x, oc = threadIdx.x;
  float s = cbias[oc];
  for (int c = 0; c < CIN; ++c)
    s += cw[(size_t)oc * 512 + 256 + c] * beta[l * CIN + c];
  cb[l * CIN + oc] = s;
}

// ---------------------------------------------------------------------------
// out[b,oc,Y,X] = sum_c cw[oc,c]*f[b,c,Y,X] + bilinear(g16[b,oc])(Y,X) + cb[oc]
// 32 oc per block; grid = BS*8*chunks
__global__ __launch_bounds__(256) void k_out(
    const float* __restrict__ f, const float* __restrict__ cw,
    const float* __restrict__ g16, const float* __restrict__ cb,
    float* __restrict__ out, int S, int shift, int chunks) {
  int blk = blockIdx.x;
  int ch = blk % chunks;
  int t = blk / chunks;
  int ocg = t & 7, b = t >> 3;
  int pix = ch * 256 + threadIdx.x;
  int SS = S * S;
  if (pix >= SS) return;
  int X = pix & (S - 1), Y = pix >> shift;
  float acc[32] = {};
  const float* fb = f + (size_t)b * CIN * SS + pix;
  for (int c = 0; c < CIN; ++c) {
    float fv = fb[(size_t)c * SS];
#pragma unroll
    for (int o = 0; o < 32; ++o)
      acc[o] += cw[(size_t)(ocg * 32 + o) * 512 + c] * fv;
  }
  float cyf = (float)(Y * 15) / (float)(S - 1);
  int ylo = imin((int)cyf, 14); float fy = cyf - (float)ylo;
  float cxf = (float)(X * 15) / (float)(S - 1);
  int xlo = imin((int)cxf, 14); float fx = cxf - (float)xlo;
  const float* gb = g16 + ((size_t)b * CIN + ocg * 32) * HW + ylo * 16 + xlo;
#pragma unroll
  for (int o = 0; o < 32; ++o) {
    const float* g = gb + (size_t)o * HW;
    float v0 = g[0], v1 = g[1], v2 = g[16], v3 = g[17];
    float bil = (1.f - fy) * ((1.f - fx) * v0 + fx * v1)
              + fy * ((1.f - fx) * v2 + fx * v3);
    out[((size_t)b * CIN + ocg * 32 + o) * SS + pix] = acc[o] + bil + cb[ocg * 32 + o];
  }
}

// ===========================================================================
extern "C" void kernel_launch(void* const* d_in, const int* in_sizes, int n_in,
                              void* d_out, int out_size, void* d_ws, size_t ws_size,
                              hipStream_t stream) {
  const float* feat[5];
  for (int l = 0; l < 5; ++l) feat[l] = (const float*)d_in[l];
  const float* att   = (const float*)d_in[5];
  const float* ktw   = (const float*)d_in[6];
  const float* ktb   = (const float*)d_in[7];
  const float* vtw   = (const float*)d_in[8];
  const float* vtb   = (const float*)d_in[9];
  const float* kqw   = (const float*)d_in[10];
  const float* kqb   = (const float*)d_in[11];
  const float* vqw   = (const float*)d_in[12];
  const float* vqb   = (const float*)d_in[13];
  const float* gamma = (const float*)d_in[14];
  const float* beta  = (const float*)d_in[15];
  const float* cw    = (const float*)d_in[16];
  const float* cbias = (const float*)d_in[17];
  float* out = (float*)d_out;

  // workspace layout (floats)
  float* ws    = (float*)d_ws;
  float* kt    = ws;                  // 10*32*256      = 81920
  float* vt    = kt   + 81920;        // 10*128*256     = 327680
  float* fr    = vt   + 327680;       // 4*256*256      = 262144
  float* kq    = fr   + 262144;       // 4*32*256       = 32768
  float* f16   = kq   + 32768;        // 4*256*256      = 262144
  float* p     = f16  + 262144;       // 4*10*256*256   = 2621440 (aliased as conv partials)
  float* mo    = p    + 2621440;      // 10240
  float* so    = mo   + 10240;        // 10240
  float* mpart = so   + 10240;        // 40960
  float* spart = mpart+ 40960;        // 40960
  float* aggn  = spart+ 40960;        // 4*10*128*256   = 1310720
  float* g16   = aggn + 1310720;      // 262144
  float* cb    = g16  + 262144;       // 1280
  float* part  = p;                   // conv partials alias p (max 8*10*128*256 = 2621440)

  static const int sizes[5]  = {64, 32, 16, 8, 4};
  static const int shifts[5] = {6, 5, 4, 3, 2};
  size_t out_off[5], fa_off[5];
  {
    size_t off = 0;
    for (int l = 0; l < 5; ++l) { out_off[l] = off; off += (size_t)BS * CIN * sizes[l] * sizes[l]; }
    for (int l = 0; l < 5; ++l) { fa_off[l] = off; off += (size_t)BS * NCLS * HW * sizes[l] * sizes[l]; }
  }

  // templates (shared across levels)
  k_conv_part<<<NCLS * (KD / 8) * KS, 256, 0, stream>>>(att, ktw, part, KD, NCLS);
  k_conv_red<<<NCLS * KD * HW / 256, 256, 0, stream>>>(part, ktb, kt, KD, NCLS, KD, 1.f);
  k_conv_part<<<NCLS * (VD / 8) * KS, 256, 0, stream>>>(att, vtw, part, VD, NCLS);
  k_conv_red<<<NCLS * VD * HW / 256, 256, 0, stream>>>(part, vtb, vt, VD, NCLS, VD, 1.f);
  k_cb<<<5, 256, 0, stream>>>(cw, cbias, beta, cb);

  for (int l = 0; l < 5; ++l) {
    int S = sizes[l], sh = shifts[l], SS = S * S;
    k_resize16<<<(BS * CIN * HW) / 256, 256, 0, stream>>>(feat[l], fr, BS * CIN * HW, S, S);
    k_conv_part<<<BS * (KD / 8) * KS, 256, 0, stream>>>(
        fr, kqw + (size_t)l * KD * CIN * 9, part, KD, BS);
    k_conv_red<<<BS * KD * HW / 256, 256, 0, stream>>>(
        part, kqb + l * KD, kq, KD, BS, KD, 1.f);
    k_conv_part<<<BS * (VD / 8) * KS, 256, 0, stream>>>(
        fr, vqw + (size_t)l * VD * CIN * 9, part, VD, BS);
    k_conv_red<<<BS * VD * HW / 256, 256, 0, stream>>>(
        part, vqb + l * VD, f16, VD, BS, CIN, (float)NCLS);
    k_pms_part<<<BS * NCLS * 4, 256, 0, stream>>>(kq, kt, p, mpart, spart);
    k_msmerge<<<BS * NCLS, 256, 0, stream>>>(mpart, spart, mo, so);
    k_pnorm<<<(BS * NCLS * HW * HW) / 256, 256, 0, stream>>>(p, mo, so);
    int fatot = BS * NCLS * HW * SS;
    k_fa4<<<fatot / 1024, 256, 0, stream>>>(p, out + fa_off[l], S, sh);
    k_aggn<<<BS * NCLS * 8, 256, 0, stream>>>(vt, p, aggn);
    k_aggred<<<(BS * VD * HW) / 256, 256, 0, stream>>>(aggn, f16);
    k_g16<<<BS * 32, 256, 0, stream>>>(f16, cw, gamma + l * CIN, g16);
    int chunks = (SS + 255) / 256;
    k_out<<<BS * 8 * chunks, 256, 0, stream>>>(
        feat[l], cw, g16, cb + l * CIN, out + out_off[l], S, sh, chunks);
  }
}

// Round 3
// 1212.162 us; speedup vs baseline: 4.4884x; 1.8058x over previous
//
#include <hip/hip_runtime.h>

// Problem constants
constexpr int CIN   = 256;   // feature channels
constexpr int KD    = 32;    // key dim
constexpr int VD    = 128;   // value dim
constexpr int NCLS  = 10;
constexpr int BS    = 4;
constexpr int HW    = 256;   // 16*16
constexpr int NJOBS = 30;    // 5 levels * 4 images + 10 template images
constexpr float BNC = 0.9999950000374997f; // 1/sqrt(1+1e-5)

static __device__ __forceinline__ int imin(int a, int b) { return a < b ? a : b; }

// ---------------------------------------------------------------------------
// Batched conv3x3 partial over 30 "jobs": jobs 0..19 = level images (in=fr_all,
// w per level), jobs 20..29 = template images (in=att, single w).
// KS_ = input-channel splits, CPB = 256/KS_. grid = NJOBS * (OC/8) * KS_.
template<int KS_>
__global__ __launch_bounds__(256) void k_conv_part(
    const float* __restrict__ in_lvl, const float* __restrict__ in_tmpl,
    const float* __restrict__ w_lvl, const float* __restrict__ w_tmpl,
    float* __restrict__ part, int OC) {
  constexpr int CPB = 256 / KS_;
  int nt  = OC >> 3;
  int job = blockIdx.x / (nt * KS_);
  int rem = blockIdx.x % (nt * KS_);
  int ks  = rem / nt, ocg = rem % nt;
  int tid = threadIdx.x;
  int y = tid >> 4, x = tid & 15;

  __shared__ float sm[8][18][18];
  for (int i = tid; i < 8 * 18 * 18; i += 256) ((float*)sm)[i] = 0.f;

  float acc[8] = {};
  const float* inb = (job < 20 ? in_lvl + (size_t)job * CIN * HW
                               : in_tmpl + (size_t)(job - 20) * CIN * HW)
                     + (size_t)ks * CPB * HW;
  const float* w0  = (job < 20 ? w_lvl + (size_t)(job >> 2) * OC * CIN * 9 : w_tmpl);
  const float* wb  = w0 + ((size_t)(ocg * 8) * CIN + ks * CPB) * 9;

  for (int cg = 0; cg < CPB / 8; ++cg) {
    __syncthreads();
#pragma unroll
    for (int pch = 0; pch < 8; ++pch)
      sm[pch][y + 1][x + 1] = inb[(cg * 8 + pch) * HW + tid];
    __syncthreads();
#pragma unroll
    for (int pch = 0; pch < 8; ++pch) {
      float r0 = sm[pch][y][x],     r1 = sm[pch][y][x + 1],     r2 = sm[pch][y][x + 2];
      float r3 = sm[pch][y + 1][x], r4 = sm[pch][y + 1][x + 1], r5 = sm[pch][y + 1][x + 2];
      float r6 = sm[pch][y + 2][x], r7 = sm[pch][y + 2][x + 1], r8 = sm[pch][y + 2][x + 2];
      int c = cg * 8 + pch;
#pragma unroll
      for (int o = 0; o < 8; ++o) {
        const float* wp = wb + ((size_t)o * CIN + c) * 9;   // wave-uniform -> s_load
        acc[o] += wp[0] * r0 + wp[1] * r1 + wp[2] * r2
                + wp[3] * r3 + wp[4] * r4 + wp[5] * r5
                + wp[6] * r6 + wp[7] * r7 + wp[8] * r8;
      }
    }
  }
  for (int o = 0; o < 8; ++o)
    part[(((size_t)ks * NJOBS + job) * OC + ocg * 8 + o) * HW + tid] = acc[o];
}

// reduce over KS partials, add bias, scale. total = NJOBS*OC*HW.
// jobs<20 -> out_lvl[(job*outC_lvl + oc)*HW + px], bias per level, *scale_lvl
// jobs>=20 -> out_tmpl[((job-20)*OC + oc)*HW + px], bias_tmpl, *1
template<int KS_>
__global__ __launch_bounds__(256) void k_conv_red(
    const float* __restrict__ part,
    const float* __restrict__ bias_lvl, const float* __restrict__ bias_tmpl,
    float* __restrict__ out_lvl, float* __restrict__ out_tmpl,
    int OC, int outC_lvl, float scale_lvl) {
  int idx = blockIdx.x * 256 + threadIdx.x;
  int px  = idx & 255;
  int oc  = (idx >> 8) % OC;
  int job = idx / (OC * HW);
  size_t stride = (size_t)NJOBS * OC * HW;
  const float* pp = part + idx;
  float s = 0.f;
#pragma unroll
  for (int k = 0; k < KS_; ++k) s += pp[k * stride];
  if (job < 20)
    out_lvl[((size_t)job * outC_lvl + oc) * HW + px] =
        (s + bias_lvl[(job >> 2) * OC + oc]) * scale_lvl;
  else
    out_tmpl[((size_t)(job - 20) * OC + oc) * HW + px] = s + bias_tmpl[oc];
}

// ---------------------------------------------------------------------------
// resize all 5 levels' features to 16x16: fr_all[l*4+b][c][256].
// grid = 5*4*256 planes, block = 256 px.
__global__ __launch_bounds__(256) void k_resize_all(
    const float* __restrict__ f0, const float* __restrict__ f1,
    const float* __restrict__ f2, const float* __restrict__ f3,
    const float* __restrict__ f4, float* __restrict__ fr_all) {
  int plane = blockIdx.x, px = threadIdx.x;
  int l = plane >> 10, pb = plane & 1023;
  int S = 64 >> l;
  const float* fin;
  switch (l) {
    case 0: fin = f0; break; case 1: fin = f1; break; case 2: fin = f2; break;
    case 3: fin = f3; break; default: fin = f4; break;
  }
  fin += (size_t)pb * S * S;
  int Y = px >> 4, X = px & 15;
  float cyf = (float)(Y * (S - 1)) / 15.0f;
  int ylo = imin((int)cyf, S - 2); float fy = cyf - (float)ylo;
  float cxf = (float)(X * (S - 1)) / 15.0f;
  int xlo = imin((int)cxf, S - 2); float fx = cxf - (float)xlo;
  float v0 = fin[ylo * S + xlo],       v1 = fin[ylo * S + xlo + 1];
  float v2 = fin[(ylo + 1) * S + xlo], v3 = fin[(ylo + 1) * S + xlo + 1];
  fr_all[(size_t)plane * HW + px] =
      (1.f - fy) * ((1.f - fx) * v0 + fx * v1) + fy * ((1.f - fx) * v2 + fx * v3);
}

// ---------------------------------------------------------------------------
// Fused p: scores + softmax(over i) + normalized write, one level.
// grid = 40*4 (bn, jt); block = 256 = 4 iq-waves x 64 j.
// p[bn][i][j] = exp(score - m_j) / s_j
__global__ __launch_bounds__(256) void k_p_fused(
    const float* __restrict__ kq_lvl, const float* __restrict__ ktb,
    float* __restrict__ p) {
  int bn = blockIdx.x >> 2, jt = blockIdx.x & 3;
  int b = bn / NCLS, n = bn % NCLS;
  int t = threadIdx.x;
  int iq = t >> 6, jl = t & 63;
  int j = jt * 64 + jl;

  __shared__ float kqs[KD][HW];   // 32 KB; reused for stats after compute
  float ktr[KD];
#pragma unroll
  for (int k = 0; k < KD; ++k) ktr[k] = ktb[((size_t)n * KD + k) * HW + j];
  const float* kqb = kq_lvl + (size_t)b * KD * HW;
  for (int s = t; s < KD * HW; s += 256) ((float*)kqs)[s] = kqb[s];
  __syncthreads();

  float v[64];
#pragma unroll
  for (int ii = 0; ii < 64; ++ii) v[ii] = 0.f;
  for (int k = 0; k < KD; ++k) {
    float a = ktr[k];
    const float4* q4 = (const float4*)&kqs[k][iq * 64];
#pragma unroll
    for (int q = 0; q < 16; ++q) {
      float4 u = q4[q];
      v[q * 4 + 0] += u.x * a; v[q * 4 + 1] += u.y * a;
      v[q * 4 + 2] += u.z * a; v[q * 4 + 3] += u.w * a;
    }
  }
  // per-thread partial stats over its 64 i's
  float ml = -1e30f;
#pragma unroll
  for (int ii = 0; ii < 64; ++ii) ml = fmaxf(ml, v[ii]);
  float sl = 0.f;
#pragma unroll
  for (int ii = 0; ii < 64; ++ii) sl += __expf(v[ii] - ml);

  __syncthreads();                 // all waves done reading kqs
  float* red = (float*)kqs;        // [0..255]=m, [256..511]=s
  red[iq * 64 + jl] = ml;
  red[256 + iq * 64 + jl] = sl;
  __syncthreads();
  float M = -1e30f;
#pragma unroll
  for (int q = 0; q < 4; ++q) M = fmaxf(M, red[q * 64 + jl]);
  float S = 0.f;
#pragma unroll
  for (int q = 0; q < 4; ++q) S += red[256 + q * 64 + jl] * __expf(red[q * 64 + jl] - M);
  float inv = 1.0f / S;

  float* pb = p + (size_t)bn * HW * HW + j;
#pragma unroll
  for (int ii = 0; ii < 64; ++ii)
    pb[(size_t)(iq * 64 + ii) * HW] = __expf(v[ii] - M) * inv;
}

// ---------------------------------------------------------------------------
// fa via LDS transpose: block = (bn, jg of 16 j's). Stage p[:,16j] tile,
// emit 16*S*S pixels with coalesced float4 stores.
__global__ __launch_bounds__(256) void k_fa_t(
    const float* __restrict__ p, float* __restrict__ out, int S, int shift) {
  int bn = blockIdx.x >> 4, jg = blockIdx.x & 15;
  int tid = threadIdx.x;
  __shared__ float ld[256][17];
  const float* pb = p + (size_t)bn * HW * HW + jg * 16;
  for (int t = tid; t < 4096; t += 256)
    ld[t >> 4][t & 15] = pb[(size_t)(t >> 4) * HW + (t & 15)];
  __syncthreads();

  int SS = S * S, tot = SS << 4;
  for (int base = tid * 4; base < tot; base += 1024) {
    int jj = base >> (2 * shift);
    int rest = base & (SS - 1);
    int X0 = rest & (S - 1), Y = rest >> shift;
    float cyf = (float)(Y * 15) / (float)(S - 1);
    int ylo = imin((int)cyf, 14); float fy = cyf - (float)ylo;
    float4 r; float* rr = (float*)&r;
#pragma unroll
    for (int t4 = 0; t4 < 4; ++t4) {
      int X = X0 + t4;
      float cxf = (float)(X * 15) / (float)(S - 1);
      int xlo = imin((int)cxf, 14); float fx = cxf - (float)xlo;
      int i00 = ylo * 16 + xlo;
      float v0 = ld[i00][jj],      v1 = ld[i00 + 1][jj];
      float v2 = ld[i00 + 16][jj], v3 = ld[i00 + 17][jj];
      rr[t4] = (1.f - fy) * ((1.f - fx) * v0 + fx * v1)
             + fy * ((1.f - fx) * v2 + fx * v3);
    }
    *(float4*)(out + ((size_t)bn * HW + jg * 16 + jj) * SS + rest) = r;
  }
}

// ---------------------------------------------------------------------------
// aggn[bn,c,j] = sum_i vt[n,c,i] * p[bn,i,j]. grid = 40*8 (ctile 16)
__global__ __launch_bounds__(256) void k_aggn(
    const float* __restrict__ vt, const float* __restrict__ p, float* __restrict__ aggn) {
  int blk = blockIdx.x;
  int ct = blk & 7, bn = blk >> 3;
  int n = bn % NCLS;
  int j = threadIdx.x;
  __shared__ float vts[16][HW];
  for (int c = 0; c < 16; ++c) vts[c][j] = vt[((size_t)n * VD + ct * 16 + c) * HW + j];
  __syncthreads();
  float acc[16] = {};
  const float* pp = p + (size_t)bn * HW * HW + j;
  for (int i = 0; i < HW; ++i) {
    float pv = pp[(size_t)i * HW];
#pragma unroll
    for (int c = 0; c < 16; ++c) acc[c] += vts[c][i] * pv;
  }
  for (int c = 0; c < 16; ++c)
    aggn[((size_t)bn * VD + ct * 16 + c) * HW + j] = acc[c];
}

// f16[b, 128+c, j] = sum_n aggn[b,n,c,j].  total = BS*VD*HW = 131072
__global__ __launch_bounds__(256) void k_aggred(
    const float* __restrict__ aggn, float* __restrict__ f16) {
  int idx = blockIdx.x * 256 + threadIdx.x;
  int j = idx & 255;
  int c = (idx >> 8) & 127;
  int b = idx >> 15;
  float s = 0.f;
#pragma unroll
  for (int n = 0; n < NCLS; ++n)
    s += aggn[(((size_t)b * NCLS + n) * VD + c) * HW + j];
  f16[((size_t)b * CIN + VD + c) * HW + j] = s;
}

// ---------------------------------------------------------------------------
// g16_all[l,b,oc,j] = sum_c cw[oc,256+c]*(gamma[l,c]*BNC)*f16_all[l,b,c,j]
// grid = 5*4*32 (8 oc per block)
__global__ __launch_bounds__(256) void k_g16_all(
    const float* __restrict__ f16_all, const float* __restrict__ cw,
    const float* __restrict__ gamma, float* __restrict__ g16_all) {
  int blk = blockIdx.x;
  int l = blk >> 7, b = (blk >> 5) & 3, ocg = blk & 31;
  int j = threadIdx.x;
  const float* f16 = f16_all + (size_t)(l * 4 + b) * CIN * HW;
  const float* gm  = gamma + l * CIN;
  float acc[8] = {};
  for (int c = 0; c < CIN; ++c) {
    float fv = f16[(size_t)c * HW + j] * (gm[c] * BNC);
#pragma unroll
    for (int o = 0; o < 8; ++o)
      acc[o] += cw[(size_t)(ocg * 8 + o) * 512 + 256 + c] * fv;
  }
  for (int o = 0; o < 8; ++o)
    g16_all[((size_t)(l * 4 + b) * CIN + ocg * 8 + o) * HW + j] = acc[o];
}

// cb[l,oc] = combine_b[oc] + sum_c cw[oc,256+c]*beta[l,c].  grid=5, block=256
__global__ __launch_bounds__(256) void k_cb(
    const float* __restrict__ cw, const float* __restrict__ cbias,
    const float* __restrict__ beta, float* __restrict__ cb) {
  int l = blockIdx.x, oc = threadIdx.x;
  float s = cbias[oc];
  for (int c = 0; c < CIN; ++c)
    s += cw[(size_t)oc * 512 + 256 + c] * beta[l * CIN + c];
  cb[l * CIN + oc] = s;
}

// ---------------------------------------------------------------------------
// out[b,oc,Y,X] = sum_c cw[oc,c]*f[b,c,Y,X] + bilinear(g16[b,oc])(Y,X) + cb[oc]
// 32 oc per block; grid = BS*8*chunks
__global__ __launch_bounds__(256) void k_out(
    const float* __restrict__ f, const float* __restrict__ cw,
    const float* __restrict__ g16, const float* __restrict__ cb,
    float* __restrict__ out, int S, int shift, int chunks) {
  int blk = blockIdx.x;
  int ch = blk % chunks;
  int t = blk / chunks;
  int ocg = t & 7, b = t >> 3;
  int pix = ch * 256 + threadIdx.x;
  int SS = S * S;
  if (pix >= SS) return;
  int X = pix & (S - 1), Y = pix >> shift;
  float acc[32] = {};
  const float* fb = f + (size_t)b * CIN * SS + pix;
  for (int c = 0; c < CIN; ++c) {
    float fv = fb[(size_t)c * SS];
#pragma unroll
    for (int o = 0; o < 32; ++o)
      acc[o] += cw[(size_t)(ocg * 32 + o) * 512 + c] * fv;
  }
  float cyf = (float)(Y * 15) / (float)(S - 1);
  int ylo = imin((int)cyf, 14); float fy = cyf - (float)ylo;
  float cxf = (float)(X * 15) / (float)(S - 1);
  int xlo = imin((int)cxf, 14); float fx = cxf - (float)xlo;
  const float* gb = g16 + ((size_t)b * CIN + ocg * 32) * HW + ylo * 16 + xlo;
#pragma unroll
  for (int o = 0; o < 32; ++o) {
    const float* g = gb + (size_t)o * HW;
    float v0 = g[0], v1 = g[1], v2 = g[16], v3 = g[17];
    float bil = (1.f - fy) * ((1.f - fx) * v0 + fx * v1)
              + fy * ((1.f - fx) * v2 + fx * v3);
    out[((size_t)b * CIN + ocg * 32 + o) * SS + pix] = acc[o] + bil + cb[ocg * 32 + o];
  }
}

// ===========================================================================
extern "C" void kernel_launch(void* const* d_in, const int* in_sizes, int n_in,
                              void* d_out, int out_size, void* d_ws, size_t ws_size,
                              hipStream_t stream) {
  const float* feat[5];
  for (int l = 0; l < 5; ++l) feat[l] = (const float*)d_in[l];
  const float* att   = (const float*)d_in[5];
  const float* ktw   = (const float*)d_in[6];
  const float* ktb   = (const float*)d_in[7];
  const float* vtw   = (const float*)d_in[8];
  const float* vtb   = (const float*)d_in[9];
  const float* kqw   = (const float*)d_in[10];
  const float* kqb   = (const float*)d_in[11];
  const float* vqw   = (const float*)d_in[12];
  const float* vqb   = (const float*)d_in[13];
  const float* gamma = (const float*)d_in[14];
  const float* beta  = (const float*)d_in[15];
  const float* cw    = (const float*)d_in[16];
  const float* cbias = (const float*)d_in[17];
  float* out = (float*)d_out;

  // workspace layout (floats), total ~8.44M fl = 33.8 MB
  float* ws      = (float*)d_ws;
  float* kqall   = ws;                    // [30][32][256]      = 245760
  float* vt      = kqall  + 245760;       // [10][128][256]     = 327680
  float* fr_all  = vt     + 327680;       // [20][256][256]     = 1310720
  float* f16_all = fr_all + 1310720;      // [20][256][256]     = 1310720
  float* g16_all = f16_all+ 1310720;      // [20][256][256]     = 1310720
  float* cb      = g16_all+ 1310720;      // [5][256]           = 1280
  float* p       = cb     + 1280;         // [40][256][256]     = 2621440
  float* aggn    = p      + 2621440;      // [40][128][256]     = 1310720
  float* part    = p;                     // conv partials alias p+aggn (3932160)

  static const int sizes[5]  = {64, 32, 16, 8, 4};
  static const int shifts[5] = {6, 5, 4, 3, 2};
  size_t out_off[5], fa_off[5];
  {
    size_t off = 0;
    for (int l = 0; l < 5; ++l) { out_off[l] = off; off += (size_t)BS * CIN * sizes[l] * sizes[l]; }
    for (int l = 0; l < 5; ++l) { fa_off[l] = off; off += (size_t)BS * NCLS * HW * sizes[l] * sizes[l]; }
  }

  // Stage 1: resize + all convs (batched across levels + templates)
  k_resize_all<<<5 * 4 * 256, 256, 0, stream>>>(
      feat[0], feat[1], feat[2], feat[3], feat[4], fr_all);
  k_conv_part<8><<<NJOBS * (KD / 8) * 8, 256, 0, stream>>>(
      fr_all, att, kqw, ktw, part, KD);
  k_conv_red<8><<<NJOBS * KD * HW / 256, 256, 0, stream>>>(
      part, kqb, ktb, kqall, kqall + 20 * KD * HW, KD, KD, 1.f);
  k_conv_part<4><<<NJOBS * (VD / 8) * 4, 256, 0, stream>>>(
      fr_all, att, vqw, vtw, part, VD);
  k_conv_red<4><<<NJOBS * VD * HW / 256, 256, 0, stream>>>(
      part, vqb, vtb, f16_all, vt, VD, CIN, (float)NCLS);
  k_cb<<<5, 256, 0, stream>>>(cw, cbias, beta, cb);

  // Stage 2: per-level p-chain (p buffer reused)
  for (int l = 0; l < 5; ++l) {
    k_p_fused<<<40 * 4, 256, 0, stream>>>(
        kqall + (size_t)l * 4 * KD * HW, kqall + 20 * KD * HW, p);
    k_fa_t<<<40 * 16, 256, 0, stream>>>(p, out + fa_off[l], sizes[l], shifts[l]);
    k_aggn<<<40 * 8, 256, 0, stream>>>(vt, p, aggn);
    k_aggred<<<BS * VD * HW / 256, 256, 0, stream>>>(
        aggn, f16_all + (size_t)l * 4 * CIN * HW);
  }

  // Stage 3: combine
  k_g16_all<<<5 * 4 * 32, 256, 0, stream>>>(f16_all, cw, gamma, g16_all);
  for (int l = 0; l < 5; ++l) {
    int S = sizes[l], sh = shifts[l], SS = S * S;
    int chunks = (SS + 255) / 256;
    k_out<<<BS * 8 * chunks, 256, 0, stream>>>(
        feat[l], cw, g16_all + (size_t)l * 4 * CIN * HW, cb + l * CIN,
        out + out_off[l], S, sh, chunks);
  }
}